// Round 1
// baseline (72.126 us; speedup 1.0000x reference)
//
#include <hip/hip_runtime.h>

// Chamfer distance v2: B=4, N=M=4096, D=3, fp32 in, scalar fp32 out.
//
// Strategy:
//   d2(g,c) = |g|^2 + |c|^2 - 2 g.c
// Stream points staged in LDS as float4 (-2x, -2y, -2z, |c|^2)  -> per pair:
// 1 add + 3 fma + 1 min = 5 VALU ops, 1 ds_read_b128 amortized over G=8 held
// points per thread. Two symmetric directions fused in one 1024-block launch.
// Cross-block (stream-chunk) min combine via uint atomicMin (distances
// clamped >= 0, nonneg float bits are order-preserving).

#define BATCH   4
#define NPTS    4096
#define HELD_PB 256    // held points per tile/block
#define TILES   16     // NPTS / HELD_PB
#define CHUNKS  8      // stream chunks
#define CHUNK_SZ 512   // NPTS / CHUNKS
#define PHASES  8      // threads per held-group covering the chunk
#define G       8      // held points per thread (HELD_PB = (256/PHASES)*G)

__global__ __launch_bounds__(256) void chamfer_init(unsigned int* mins, float* out) {
    int i = blockIdx.x * 256 + threadIdx.x;
    if (i < 2 * BATCH * NPTS) mins[i] = 0x7F800000u;  // +inf bits
    if (i == 0) out[0] = 0.0f;
}

__global__ __launch_bounds__(256) void chamfer_pass(
    const float* __restrict__ coord, const float* __restrict__ gt,
    unsigned int* __restrict__ mins)
{
    __shared__ float4 sc[CHUNK_SZ];  // 8 KB

    int bx = blockIdx.x;
    int pass  = bx >> 9;         // 0: held=gt, stream=coord (match_gt)
    int r     = bx & 511;        // 1: held=coord, stream=gt (match_coord)
    int b     = r >> 7;
    int tile  = (r >> 3) & 15;
    int chunk = r & 7;

    const float* held = pass ? coord : gt;
    const float* strm = pass ? gt : coord;
    unsigned int* out = mins + pass * (BATCH * NPTS) + b * NPTS;

    int tid = threadIdx.x;

    // ---- stage stream chunk into LDS as (-2x, -2y, -2z, |c|^2) ----
    const float* sbase = strm + (size_t)b * NPTS * 3 + (size_t)chunk * CHUNK_SZ * 3;
    for (int p = tid; p < CHUNK_SZ; p += 256) {
        float x = sbase[p * 3 + 0];
        float y = sbase[p * 3 + 1];
        float z = sbase[p * 3 + 2];
        sc[p] = make_float4(-2.f * x, -2.f * y, -2.f * z, x * x + y * y + z * z);
    }

    // ---- load G held points into registers ----
    int hg = tid >> 3;   // 0..31 held group
    int ph = tid & 7;    // 0..7 phase (low lane bits -> shfl_xor group)
    const float* hbase = held + (size_t)b * NPTS * 3;
    int hofs = tile * HELD_PB + hg;

    float hx[G], hy[G], hz[G], h2[G], mn[G];
#pragma unroll
    for (int g = 0; g < G; ++g) {
        int h = hofs + g * 32;
        float x = hbase[h * 3 + 0];
        float y = hbase[h * 3 + 1];
        float z = hbase[h * 3 + 2];
        hx[g] = x; hy[g] = y; hz[g] = z;
        h2[g] = x * x + y * y + z * z;
        mn[g] = INFINITY;
    }
    __syncthreads();

    // ---- main loop: 64 iters x (1 ds_read_b128 + 8x5 VALU) ----
#pragma unroll 4
    for (int it = 0; it < CHUNK_SZ / PHASES; ++it) {
        float4 c = sc[it * PHASES + ph];
#pragma unroll
        for (int g = 0; g < G; ++g) {
            float t = h2[g] + c.w;
            t = fmaf(c.x, hx[g], t);
            t = fmaf(c.y, hy[g], t);
            t = fmaf(c.z, hz[g], t);
            mn[g] = fminf(mn[g], t);
        }
    }

    // ---- reduce min over the 8 phases (lane bits 0..2) ----
#pragma unroll
    for (int g = 0; g < G; ++g) {
        float v = mn[g];
        v = fminf(v, __shfl_xor(v, 1));
        v = fminf(v, __shfl_xor(v, 2));
        v = fminf(v, __shfl_xor(v, 4));
        mn[g] = v;
    }

    if (ph == 0) {
#pragma unroll
        for (int g = 0; g < G; ++g) {
            unsigned int bits = __float_as_uint(fmaxf(mn[g], 0.0f));
            atomicMin(&out[hofs + g * 32], bits);
        }
    }
}

__global__ __launch_bounds__(256) void chamfer_final(
    const unsigned int* __restrict__ mins, float* __restrict__ out)
{
    __shared__ float wsum[4];
    int tid = threadIdx.x;
    int base = blockIdx.x * 2048 + tid;
    float s = 0.f;
#pragma unroll
    for (int k = 0; k < 8; ++k)
        s += __uint_as_float(mins[base + k * 256]);
    // wave64 reduce
    for (int off = 32; off > 0; off >>= 1)
        s += __shfl_down(s, off);
    if ((tid & 63) == 0) wsum[tid >> 6] = s;
    __syncthreads();
    if (tid == 0) {
        float t = wsum[0] + wsum[1] + wsum[2] + wsum[3];
        atomicAdd(out, t * (1.0f / 16384.0f));  // 1/(B*NPTS), same for both means
    }
}

extern "C" void kernel_launch(void* const* d_in, const int* in_sizes, int n_in,
                              void* d_out, int out_size, void* d_ws, size_t ws_size,
                              hipStream_t stream) {
    const float* coord = (const float*)d_in[0];  // [4,4096,3]
    const float* gt    = (const float*)d_in[1];  // [4,4096,3]
    float* out = (float*)d_out;
    unsigned int* mins = (unsigned int*)d_ws;    // 2*4*4096 uints = 128 KB

    chamfer_init<<<(2 * BATCH * NPTS + 255) / 256, 256, 0, stream>>>(mins, out);
    chamfer_pass<<<2 * BATCH * TILES * CHUNKS, 256, 0, stream>>>(coord, gt, mins);
    chamfer_final<<<16, 256, 0, stream>>>(mins, out);
}

// Round 2
// 71.866 us; speedup vs baseline: 1.0036x; 1.0036x over previous
//
#include <hip/hip_runtime.h>

// Chamfer distance v2: B=4, N=M=4096, D=3, fp32 in, scalar fp32 out.
//
// R2 structure: 2 dispatches, no workspace mins, no global atomics.
//   pass:  512 blocks = 2 dirs x 4 batches x 64 held-tiles (64 pts each).
//          Each block scans the FULL 4096-pt stream (LDS double-buffered,
//          8 chunks x 512 pts, 1 barrier/chunk), so per-held-point mins are
//          block-local. d2(h,c) = |h|^2 + (|c|^2 - 2 c.h) with stream staged
//          as (-2x,-2y,-2z,|c|^2): 5 VALU/pair, 1 ds_read_b128 per 8 pairs.
//          LDS index padded p -> p + (p>>3) to kill the 4-way bank aliasing
//          of 32 consecutive float4 reads (pad folds into per-thread const).
//          Block reduces 64 mins -> 1 partial sum, plain store.
//   final: 1 block sums 512 partials, writes out[0] (no accumulation, so no
//          zero-init of d_out needed).

#define BATCH 4
#define NPTS  4096
#define TILE  64            // held points per block
#define CH    512           // stream chunk size
#define NCH   8             // NPTS / CH
#define PHN   32            // phases (threads per held-group)
#define G     8             // held points per thread
#define CHP   (CH + CH/8)   // padded chunk: 576 float4 = 9 KB

__device__ __forceinline__ int pad_idx(int p) { return p + (p >> 3); }

__global__ __launch_bounds__(256, 2) void chamfer_pass(
    const float* __restrict__ coord, const float* __restrict__ gt,
    float* __restrict__ partials)
{
    __shared__ float4 sc[2][CHP];   // 18 KB
    __shared__ float bsum[8];

    int bx   = blockIdx.x;
    int pass = bx >> 8;            // 0: held=gt/stream=coord, 1: reverse
    int r    = bx & 255;
    int b    = r >> 6;
    int tile = r & 63;

    const float* hbase = (pass ? coord : gt) + b * NPTS * 3;
    const float* sbase = (pass ? gt : coord) + b * NPTS * 3;

    int tid   = threadIdx.x;
    int hg    = tid >> 5;          // 0..7 held group
    int ph    = tid & 31;          // 0..31 phase (stays in 32-lane shfl half)
    int phofs = ph + (ph >> 3);    // padded per-thread LDS offset

    // ---- held points -> registers (broadcast loads across phases) ----
    float hx[G], hy[G], hz[G], h2[G], mn[G];
    int h0 = tile * TILE + hg * G;
#pragma unroll
    for (int g = 0; g < G; ++g) {
        float x = hbase[(h0 + g) * 3 + 0];
        float y = hbase[(h0 + g) * 3 + 1];
        float z = hbase[(h0 + g) * 3 + 2];
        hx[g] = x; hy[g] = y; hz[g] = z;
        h2[g] = x * x + y * y + z * z;
        mn[g] = INFINITY;
    }

    // ---- stage chunk 0 ----
    {
        int p = tid * 2;
        const float* s0 = sbase + p * 3;
        float x0 = s0[0], y0 = s0[1], z0 = s0[2];
        float x1 = s0[3], y1 = s0[4], z1 = s0[5];
        sc[0][pad_idx(p)]     = make_float4(-2.f*x0, -2.f*y0, -2.f*z0, x0*x0 + y0*y0 + z0*z0);
        sc[0][pad_idx(p + 1)] = make_float4(-2.f*x1, -2.f*y1, -2.f*z1, x1*x1 + y1*y1 + z1*z1);
    }
    __syncthreads();

    for (int ch = 0; ch < NCH; ++ch) {
        // prefetch next chunk into the other buffer (writes land before the
        // barrier below; that buffer's readers finished at the prior barrier)
        if (ch + 1 < NCH) {
            int p = tid * 2;
            const float* s0 = sbase + ((ch + 1) * CH + p) * 3;
            float x0 = s0[0], y0 = s0[1], z0 = s0[2];
            float x1 = s0[3], y1 = s0[4], z1 = s0[5];
            int nb = (ch + 1) & 1;
            sc[nb][pad_idx(p)]     = make_float4(-2.f*x0, -2.f*y0, -2.f*z0, x0*x0 + y0*y0 + z0*z0);
            sc[nb][pad_idx(p + 1)] = make_float4(-2.f*x1, -2.f*y1, -2.f*z1, x1*x1 + y1*y1 + z1*z1);
        }

        const float4* cur = sc[ch & 1];
#pragma unroll 4
        for (int it = 0; it < CH / PHN; ++it) {
            float4 c = cur[it * (PHN + PHN / 8) + phofs];  // = pad_idx(it*32+ph)
#pragma unroll
            for (int g = 0; g < G; ++g) {
                float t = h2[g] + c.w;
                t = fmaf(c.x, hx[g], t);
                t = fmaf(c.y, hy[g], t);
                t = fmaf(c.z, hz[g], t);
                mn[g] = fminf(mn[g], t);
            }
        }
        __syncthreads();
    }

    // ---- reduce min over the 32 phases (lane bits 0..4), sum over g ----
    float s = 0.f;
#pragma unroll
    for (int g = 0; g < G; ++g) {
        float v = mn[g];
        v = fminf(v, __shfl_xor(v, 16));
        v = fminf(v, __shfl_xor(v, 8));
        v = fminf(v, __shfl_xor(v, 4));
        v = fminf(v, __shfl_xor(v, 2));
        v = fminf(v, __shfl_xor(v, 1));
        s += fmaxf(v, 0.f);   // true d^2 >= 0; clamp fp cancellation
    }
    if (ph == 0) bsum[hg] = s;
    __syncthreads();
    if (tid == 0) {
        float t = 0.f;
#pragma unroll
        for (int i = 0; i < 8; ++i) t += bsum[i];
        partials[bx] = t;
    }
}

__global__ __launch_bounds__(512) void chamfer_final(
    const float* __restrict__ partials, float* __restrict__ out)
{
    __shared__ float wsum[8];
    int tid = threadIdx.x;
    float s = partials[tid];
#pragma unroll
    for (int off = 32; off > 0; off >>= 1)
        s += __shfl_down(s, off);
    if ((tid & 63) == 0) wsum[tid >> 6] = s;
    __syncthreads();
    if (tid == 0) {
        float t = 0.f;
#pragma unroll
        for (int i = 0; i < 8; ++i) t += wsum[i];
        out[0] = t * (1.0f / 16384.0f);  // 1/(B*NPTS), same for both means
    }
}

extern "C" void kernel_launch(void* const* d_in, const int* in_sizes, int n_in,
                              void* d_out, int out_size, void* d_ws, size_t ws_size,
                              hipStream_t stream) {
    const float* coord = (const float*)d_in[0];  // [4,4096,3]
    const float* gt    = (const float*)d_in[1];  // [4,4096,3]
    float* partials = (float*)d_ws;              // 512 floats
    float* out = (float*)d_out;

    chamfer_pass<<<512, 256, 0, stream>>>(coord, gt, partials);
    chamfer_final<<<1, 512, 0, stream>>>(partials, out);
}